// Round 12
// baseline (889.287 us; speedup 1.0000x reference)
//
#include <hip/hip_runtime.h>
#include <math.h>

#define Lc 13
#define Hc 1024
#define Bc 32
#define Sc 2048
#define BSc (Bc*Sc)
#define CHUNK 128
#define NCHUNK 16
#define NBLK (Bc*NCHUNK)   // 512 chunk blocks

#define INV_LN2 1.44269504088896340736f
#define LN2f    0.69314718055994530942f

#if __has_builtin(__builtin_amdgcn_exp2f)
#define EXP2F(x) __builtin_amdgcn_exp2f(x)
#else
#define EXP2F(x) exp2f(x)
#endif
#if __has_builtin(__builtin_amdgcn_logf)
#define LOG2F(x) __builtin_amdgcn_logf(x)
#else
#define LOG2F(x) log2f(x)
#endif

// DPP-based partial butterfly: v += lane-permuted v (VALU only, no LDS).
template <int CTRL>
__device__ __forceinline__ float dpp_add(float v) {
  int p = __builtin_amdgcn_update_dpp(0, __float_as_int(v), CTRL, 0xF, 0xF, true);
  return v + __int_as_float(p);
}

// ---------------------------------------------------------------------------
// Kernel A: logits = hs @ W^T + b.  R10 structure (LDS W + DPP reduce, the
// proven best) with G=4 row-groups per wave (16 rows/wave): the 13
// ds_read_b128 per slice are shared by 4x as many rows, halving per-CU LDS
// busy (33->17us) below the 43us HBM A-stream floor. R11 lesson: no-LDS W
// needs ~100 VGPR of in-flight loads; (256,8)'s 64-cap made the compiler
// serialize at VGPR=32 -> 219us. ILP > occupancy here.
// Lane = rin*16+ch; rows rowBase + g*4 + rin, g=0..3. 16 slices of 64 h.
// Depth-2 prefetch, 3-slot rotation, all indices compile-time (rule #20).
// Grid 512 = exactly 2 blocks/CU (106KB LDS), zero tail. (512,4): 128 VGPR
// cap, hand-count ~115 -> no spill (watch WRITE_SIZE ~3.5MB as tripwire).
// ---------------------------------------------------------------------------
__global__ __launch_bounds__(512, 4)
void k_logits(const float* __restrict__ A, const float* __restrict__ W,
              const float* __restrict__ bias, float* __restrict__ out) {
  __shared__ float Wl[Lc * Hc];   // 53.2 KB
  const int tid = threadIdx.x;
  const int ln  = tid & 63;
  const int wv  = tid >> 6;            // 0..7
  const int rin = ln >> 4;             // row within 4-row group
  const int ch  = ln & 15;             // 16B chunk within 64-float slice
  const size_t rowBase = (size_t)blockIdx.x * 128 + (size_t)wv * 16;

  const float* Ag0 = A + (rowBase + 0  + rin) * (size_t)Hc + ch * 4;
  const float* Ag1 = A + (rowBase + 4  + rin) * (size_t)Hc + ch * 4;
  const float* Ag2 = A + (rowBase + 8  + rin) * (size_t)Hc + ch * 4;
  const float* Ag3 = A + (rowBase + 12 + rin) * (size_t)Hc + ch * 4;

  // ---- depth-2 prefetch: slices 0,1 for all 4 groups, before W-stage ----
  float4 sl[4][3];
  sl[0][0] = *(const float4*)(Ag0);      sl[0][1] = *(const float4*)(Ag0 + 64);
  sl[1][0] = *(const float4*)(Ag1);      sl[1][1] = *(const float4*)(Ag1 + 64);
  sl[2][0] = *(const float4*)(Ag2);      sl[2][1] = *(const float4*)(Ag2 + 64);
  sl[3][0] = *(const float4*)(Ag3);      sl[3][1] = *(const float4*)(Ag3 + 64);
  __builtin_amdgcn_sched_barrier(0);     // pin A prefetch before W-stage

  // ---- stage W once, coalesced float4 (3328 float4 total) ----
  {
    const float4* Wg4 = (const float4*)W;
    float4* Wl4 = (float4*)Wl;
#pragma unroll
    for (int i = 0; i < 7; ++i) {
      int idx = tid + i * 512;
      if (idx < Lc * (Hc / 4)) Wl4[idx] = Wg4[idx];
    }
  }
  __syncthreads();

  float acc[4][Lc];
#pragma unroll
  for (int g = 0; g < 4; ++g)
#pragma unroll
    for (int l = 0; l < Lc; ++l) acc[g][l] = 0.f;

#pragma unroll
  for (int kk = 0; kk < 16; ++kk) {
    // issue slice kk+2 into slot (kk+2)%3 (distinct from consume slot kk%3)
    if (kk + 2 < 16) {
      sl[0][(kk + 2) % 3] = *(const float4*)(Ag0 + (kk + 2) * 64);
      sl[1][(kk + 2) % 3] = *(const float4*)(Ag1 + (kk + 2) * 64);
      sl[2][(kk + 2) % 3] = *(const float4*)(Ag2 + (kk + 2) * 64);
      sl[3][(kk + 2) % 3] = *(const float4*)(Ag3 + (kk + 2) * 64);
    }
    const float* wb = &Wl[kk * 64 + ch * 4];
#pragma unroll
    for (int l = 0; l < Lc; ++l) {
      float4 w = *(const float4*)(wb + l * Hc);   // shared by 4 groups
#pragma unroll
      for (int g = 0; g < 4; ++g) {
        float4 a = sl[g][kk % 3];
        acc[g][l] = fmaf(a.x, w.x, acc[g][l]);
        acc[g][l] = fmaf(a.y, w.y, acc[g][l]);
        acc[g][l] = fmaf(a.z, w.z, acc[g][l]);
        acc[g][l] = fmaf(a.w, w.w, acc[g][l]);
      }
    }
  }

  // reduce within 16-lane group: xor1,xor2 (quad_perm), ^7, ^15 (mirrors)
#pragma unroll
  for (int g = 0; g < 4; ++g) {
#pragma unroll
    for (int l = 0; l < Lc; ++l) {
      float s = acc[g][l];
      s = dpp_add<0xB1>(s);
      s = dpp_add<0x4E>(s);
      s = dpp_add<0x141>(s);
      s = dpp_add<0x140>(s);
      acc[g][l] = s;
    }
    float ov = 0.f;
#pragma unroll
    for (int l = 0; l < Lc; ++l) ov = (ch == l) ? acc[g][l] + bias[l] : ov;
    if (ch < Lc) out[(rowBase + (size_t)g * 4 + rin) * Lc + ch] = ov;
  }
}

// ---------------------------------------------------------------------------
// Kernel B: per (batch, chunk) 13x13 transfer matrix, LINEAR domain
// (13 shfl + 13 fma + 1 exp2 per step; exponent-extract renorm every 8).
// Wave 0 also computes the chunk's numerator partial. Block 0 zeroes out0.
// ---------------------------------------------------------------------------
__global__ void k_chunks(const float* __restrict__ logits, const int* __restrict__ mask,
                         const int* __restrict__ labels, const float* __restrict__ T,
                         float* __restrict__ Mout, float* __restrict__ numpart,
                         float* __restrict__ cntpart, float* __restrict__ out0) {
  const int bp = blockIdx.x;
  const int b  = bp >> 4;       // NCHUNK == 16
  const int p  = bp & 15;
  const int tid = threadIdx.x;
  if (bp == 0 && tid == 0) out0[0] = 0.f;   // zero loss accumulator for k_final
  const int g = tid >> 4;
  const int k = tid & 15;
  const int kk = (k < 13) ? k : 0;
  const int gg = (g < 13) ? g : 0;
  const bool active = (g < 13) && (k < 13);
  const size_t lbase = (size_t)b * Sc;
  const int t0 = 1 + p * CHUNK;
  const int t1 = min(t0 + CHUNK, Sc);

  float U[13];   // column kk of exp(T)
#pragma unroll
  for (int j = 0; j < 13; ++j) U[j] = EXP2F(T[j * 13 + kk] * INV_LN2);

  float e0 = logits[(lbase + t0) * Lc + kk] * INV_LN2;
  int   m0 = mask[lbase + t0];
  float P = m0 ? EXP2F(T[gg * 13 + kk] * INV_LN2 + e0) : ((g == k) ? 1.f : 0.f);
  float off = 0.f;

  for (int t = t0 + 1; t < t1; ++t) {
    float e2 = logits[(lbase + t) * Lc + kk] * INV_LN2;
    int   mk = mask[lbase + t];
    float pj[13];
#pragma unroll
    for (int j = 0; j < 13; ++j) pj[j] = __shfl(P, j, 16);
    float s0 = pj[0] * U[0];  s0 = fmaf(pj[4],  U[4],  s0);
    s0 = fmaf(pj[8],  U[8],  s0);  s0 = fmaf(pj[12], U[12], s0);
    float s1 = pj[1] * U[1];  s1 = fmaf(pj[5],  U[5],  s1);  s1 = fmaf(pj[9],  U[9],  s1);
    float s2 = pj[2] * U[2];  s2 = fmaf(pj[6],  U[6],  s2);  s2 = fmaf(pj[10], U[10], s2);
    float s3 = pj[3] * U[3];  s3 = fmaf(pj[7],  U[7],  s3);  s3 = fmaf(pj[11], U[11], s3);
    float s = (s0 + s1) + (s2 + s3);
    float Pn = EXP2F(e2) * s;
    P = mk ? Pn : P;
    if (((t - t0) & 7) == 0) {   // renorm: keep row max in [1,2)
      float mx = P;
#pragma unroll
      for (int o = 1; o < 16; o <<= 1) mx = fmaxf(mx, __shfl_xor(mx, o, 16));
      unsigned eb = (__float_as_uint(mx) >> 23) & 255u;
      float scale = __uint_as_float((254u - eb) << 23);   // 2^(127-eb)
      P *= scale;
      off += (float)((int)eb - 127);
    }
  }
  if (active) Mout[(size_t)bp * 169 + g * 13 + k] = (P > 0.f) ? (LOG2F(P) + off) : -1e30f;

  // ---- numerator partial for this chunk's tokens [t0, t1) ----
  if (tid < 64) {
    float np = 0.f; int cnt = 0;
    for (int t = t0 + tid; t < t1; t += 64) {
      int mk = mask[lbase + t];
      if (mk) {
        int tg = labels[lbase + t];
        int pg = labels[lbase + t - 1];
        np += T[pg * 13 + tg] + logits[(lbase + t) * Lc + tg];
        cnt += 1;
      }
    }
#pragma unroll
    for (int o = 1; o < 64; o <<= 1) {
      np  += __shfl_xor(np, o, 64);
      cnt += __shfl_xor(cnt, o, 64);
    }
    if (tid == 0) { numpart[bp] = np; cntpart[bp] = (float)cnt; }
  }
}

// ---------------------------------------------------------------------------
// Kernel C: per batch: combine 16 chunk matrices (log2 domain) -> denominator;
// assemble numerator from partials; atomicAdd loss.
// ---------------------------------------------------------------------------
__global__ void k_final(const float* __restrict__ logits, const int* __restrict__ mask,
                        const int* __restrict__ labels, const float* __restrict__ startT,
                        const float* __restrict__ endT, const float* __restrict__ Mws,
                        const float* __restrict__ numpart, const float* __restrict__ cntpart,
                        float* __restrict__ out0) {
  const int b = blockIdx.x;
  const int lane = threadIdx.x;
  const int kk = (lane < 13) ? lane : 0;
  const size_t lbase = (size_t)b * Sc;

  // ---- denominator (log2 domain) ----
  float v = (startT[kk] + logits[lbase * Lc + kk]) * INV_LN2;
  for (int p = 0; p < NCHUNK; ++p) {
    const float* Mp = Mws + (size_t)(b * NCHUNK + p) * 169;
    float a[13];
#pragma unroll
    for (int j = 0; j < 13; ++j) a[j] = __shfl(v, j, 64) + Mp[j * 13 + kk];
    float mx = a[0];
#pragma unroll
    for (int j = 1; j < 13; ++j) mx = fmaxf(mx, a[j]);
    float s = 0.f;
#pragma unroll
    for (int j = 0; j < 13; ++j) s += EXP2F(a[j] - mx);
    v = mx + LOG2F(s);
  }
  float x = (lane < 13) ? (v + endT[kk] * INV_LN2) : -1e30f;
  float mx = x;
#pragma unroll
  for (int off = 1; off < 16; off <<= 1) mx = fmaxf(mx, __shfl_xor(mx, off, 16));
  float sx = EXP2F(x - mx);
#pragma unroll
  for (int off = 1; off < 16; off <<= 1) sx += __shfl_xor(sx, off, 16);
  float den = (mx + LOG2F(sx)) * LN2f;   // valid on lanes 0..15

  // ---- numerator from chunk partials (lanes 0..15) ----
  float np = 0.f, cs = 0.f;
  if (lane < NCHUNK) { np = numpart[b * NCHUNK + lane]; cs = cntpart[b * NCHUNK + lane]; }
#pragma unroll
  for (int o = 1; o < 16; o <<= 1) {
    np += __shfl_xor(np, o, 16);
    cs += __shfl_xor(cs, o, 16);
  }
  if (lane == 0) {
    int lab0 = labels[lbase];
    int seqlen = mask[lbase] + (int)(cs + 0.5f);
    int lastTag = labels[lbase + seqlen - 1];
    float num = startT[lab0] + logits[lbase * Lc + lab0] + np + endT[lastTag];
    float llh = num - den;
    atomicAdd(out0, -llh * (1.0f / Bc));
  }
}

extern "C" void kernel_launch(void* const* d_in, const int* in_sizes, int n_in,
                              void* d_out, int out_size, void* d_ws, size_t ws_size,
                              hipStream_t stream) {
  const float* hs     = (const float*)d_in[0];
  const int*   amask  = (const int*)d_in[1];
  const int*   labels = (const int*)d_in[2];
  const float* W      = (const float*)d_in[3];
  const float* bias   = (const float*)d_in[4];
  const float* startT = (const float*)d_in[5];
  const float* endT   = (const float*)d_in[6];
  const float* T      = (const float*)d_in[7];

  float* out    = (float*)d_out;
  float* logits = out + 1;            // output 1 follows the scalar loss
  float* Mws    = (float*)d_ws;       // 512*169 floats = 346 KB
  float* numpart = Mws + (size_t)NBLK * 169;
  float* cntpart = numpart + NBLK;    // total ~350 KB of ws

  k_logits<<<BSc / 128, 512, 0, stream>>>(hs, W, bias, logits);
  k_chunks<<<NBLK, 256, 0, stream>>>(logits, amask, labels, T, Mws, numpart, cntpart, out);
  k_final <<<Bc, 64, 0, stream>>>(logits, amask, labels, startT, endT, Mws, numpart, cntpart, out);
}

// Round 13
// 140.357 us; speedup vs baseline: 6.3359x; 6.3359x over previous
//
#include <hip/hip_runtime.h>
#include <math.h>

#define Lc 13
#define Hc 1024
#define Bc 32
#define Sc 2048
#define BSc (Bc*Sc)
#define CHUNK 128
#define NCHUNK 16
#define NBLK (Bc*NCHUNK)   // 512 chunk blocks

#define INV_LN2 1.44269504088896340736f
#define LN2f    0.69314718055994530942f

#if __has_builtin(__builtin_amdgcn_exp2f)
#define EXP2F(x) __builtin_amdgcn_exp2f(x)
#else
#define EXP2F(x) exp2f(x)
#endif
#if __has_builtin(__builtin_amdgcn_logf)
#define LOG2F(x) __builtin_amdgcn_logf(x)
#else
#define LOG2F(x) log2f(x)
#endif

// DPP-based partial butterfly: v += lane-permuted v (VALU only, no LDS).
template <int CTRL>
__device__ __forceinline__ float dpp_add(float v) {
  int p = __builtin_amdgcn_update_dpp(0, __float_as_int(v), CTRL, 0xF, 0xF, true);
  return v + __int_as_float(p);
}

// ---------------------------------------------------------------------------
// Kernel A: logits = hs @ W^T + b.  G=4 row-groups/wave (16 rows): 13
// ds_read_b128/slice serve 16 rows -> per-CU LDS busy ~17us < 43us HBM floor.
// VGPR cap table measured on this toolchain: (512,2)->128, (512,4)->64 (R12
// spilled 969MB at VGPR=64), (256,8)->64. So (512,2); LDS 53KB forces
// 2 blocks/CU regardless. Register plan ~105 < 128: acc[4][13]=52 +
// 8 float4 ping-pong bufs=32 + addr/misc. Ping-pong is STATIC by
// construction (8 iters x 2 slices, named bufA/bufB) -- immune to rule #20
// even if the outer loop doesn't unroll. Depth-1 prefetch + 4 waves/SIMD.
// Grid 512 = exactly 2 blocks/CU, zero tail.
// ---------------------------------------------------------------------------
__global__ __launch_bounds__(512, 2)
void k_logits(const float* __restrict__ A, const float* __restrict__ W,
              const float* __restrict__ bias, float* __restrict__ out) {
  __shared__ float Wl[Lc * Hc];   // 53.2 KB
  const int tid = threadIdx.x;
  const int ln  = tid & 63;
  const int wv  = tid >> 6;            // 0..7
  const int rin = ln >> 4;             // row within 4-row group
  const int ch  = ln & 15;             // 16B chunk within 64-float slice
  const size_t rowBase = (size_t)blockIdx.x * 128 + (size_t)wv * 16;

  const float* Ag0 = A + (rowBase + 0  + rin) * (size_t)Hc + ch * 4;
  const float* Ag1 = Ag0 + 4  * (size_t)Hc;
  const float* Ag2 = Ag0 + 8  * (size_t)Hc;
  const float* Ag3 = Ag0 + 12 * (size_t)Hc;

  float acc[4][Lc];
#pragma unroll
  for (int g = 0; g < 4; ++g)
#pragma unroll
    for (int l = 0; l < Lc; ++l) acc[g][l] = 0.f;

  // slice-0 prefetch into bufA, pinned before the W-stage
  float4 bA0 = *(const float4*)(Ag0);
  float4 bA1 = *(const float4*)(Ag1);
  float4 bA2 = *(const float4*)(Ag2);
  float4 bA3 = *(const float4*)(Ag3);
  __builtin_amdgcn_sched_barrier(0);

  // ---- stage W once, coalesced float4 (3328 float4 total) ----
  {
    const float4* Wg4 = (const float4*)W;
    float4* Wl4 = (float4*)Wl;
#pragma unroll
    for (int i = 0; i < 7; ++i) {
      int idx = tid + i * 512;
      if (idx < Lc * (Hc / 4)) Wl4[idx] = Wg4[idx];
    }
  }
  __syncthreads();

  auto compute = [&](int k, float4 a0, float4 a1, float4 a2, float4 a3) {
    const float* wb = &Wl[k * 64 + ch * 4];
#pragma unroll
    for (int l = 0; l < Lc; ++l) {
      float4 w = *(const float4*)(wb + l * Hc);   // one read, 16 rows served
      acc[0][l] = fmaf(a0.x, w.x, acc[0][l]); acc[0][l] = fmaf(a0.y, w.y, acc[0][l]);
      acc[0][l] = fmaf(a0.z, w.z, acc[0][l]); acc[0][l] = fmaf(a0.w, w.w, acc[0][l]);
      acc[1][l] = fmaf(a1.x, w.x, acc[1][l]); acc[1][l] = fmaf(a1.y, w.y, acc[1][l]);
      acc[1][l] = fmaf(a1.z, w.z, acc[1][l]); acc[1][l] = fmaf(a1.w, w.w, acc[1][l]);
      acc[2][l] = fmaf(a2.x, w.x, acc[2][l]); acc[2][l] = fmaf(a2.y, w.y, acc[2][l]);
      acc[2][l] = fmaf(a2.z, w.z, acc[2][l]); acc[2][l] = fmaf(a2.w, w.w, acc[2][l]);
      acc[3][l] = fmaf(a3.x, w.x, acc[3][l]); acc[3][l] = fmaf(a3.y, w.y, acc[3][l]);
      acc[3][l] = fmaf(a3.z, w.z, acc[3][l]); acc[3][l] = fmaf(a3.w, w.w, acc[3][l]);
    }
  };

  for (int k2 = 0; k2 < 8; ++k2) {          // 2 slices/iter; slots static
    const int k0 = 2 * k2, k1 = 2 * k2 + 1;
    // prefetch odd slice into bufB, then compute even slice from bufA
    float4 bB0 = *(const float4*)(Ag0 + k1 * 64);
    float4 bB1 = *(const float4*)(Ag1 + k1 * 64);
    float4 bB2 = *(const float4*)(Ag2 + k1 * 64);
    float4 bB3 = *(const float4*)(Ag3 + k1 * 64);
    compute(k0, bA0, bA1, bA2, bA3);
    // prefetch next even slice into bufA, then compute odd from bufB
    if (k2 < 7) {
      bA0 = *(const float4*)(Ag0 + (k0 + 2) * 64);
      bA1 = *(const float4*)(Ag1 + (k0 + 2) * 64);
      bA2 = *(const float4*)(Ag2 + (k0 + 2) * 64);
      bA3 = *(const float4*)(Ag3 + (k0 + 2) * 64);
    }
    compute(k1, bB0, bB1, bB2, bB3);
  }

  // reduce within 16-lane group: xor1,xor2 (quad_perm), ^7, ^15 (mirrors)
#pragma unroll
  for (int g = 0; g < 4; ++g) {
#pragma unroll
    for (int l = 0; l < Lc; ++l) {
      float s = acc[g][l];
      s = dpp_add<0xB1>(s);
      s = dpp_add<0x4E>(s);
      s = dpp_add<0x141>(s);
      s = dpp_add<0x140>(s);
      acc[g][l] = s;
    }
    float ov = 0.f;
#pragma unroll
    for (int l = 0; l < Lc; ++l) ov = (ch == l) ? acc[g][l] + bias[l] : ov;
    if (ch < Lc) out[(rowBase + (size_t)g * 4 + rin) * Lc + ch] = ov;
  }
}

// ---------------------------------------------------------------------------
// Kernel B: per (batch, chunk) 13x13 transfer matrix, LINEAR domain
// (13 shfl + 13 fma + 1 exp2 per step; exponent-extract renorm every 8).
// Wave 0 also computes the chunk's numerator partial. Block 0 zeroes out0.
// ---------------------------------------------------------------------------
__global__ void k_chunks(const float* __restrict__ logits, const int* __restrict__ mask,
                         const int* __restrict__ labels, const float* __restrict__ T,
                         float* __restrict__ Mout, float* __restrict__ numpart,
                         float* __restrict__ cntpart, float* __restrict__ out0) {
  const int bp = blockIdx.x;
  const int b  = bp >> 4;       // NCHUNK == 16
  const int p  = bp & 15;
  const int tid = threadIdx.x;
  if (bp == 0 && tid == 0) out0[0] = 0.f;   // zero loss accumulator for k_final
  const int g = tid >> 4;
  const int k = tid & 15;
  const int kk = (k < 13) ? k : 0;
  const int gg = (g < 13) ? g : 0;
  const bool active = (g < 13) && (k < 13);
  const size_t lbase = (size_t)b * Sc;
  const int t0 = 1 + p * CHUNK;
  const int t1 = min(t0 + CHUNK, Sc);

  float U[13];   // column kk of exp(T)
#pragma unroll
  for (int j = 0; j < 13; ++j) U[j] = EXP2F(T[j * 13 + kk] * INV_LN2);

  float e0 = logits[(lbase + t0) * Lc + kk] * INV_LN2;
  int   m0 = mask[lbase + t0];
  float P = m0 ? EXP2F(T[gg * 13 + kk] * INV_LN2 + e0) : ((g == k) ? 1.f : 0.f);
  float off = 0.f;

  for (int t = t0 + 1; t < t1; ++t) {
    float e2 = logits[(lbase + t) * Lc + kk] * INV_LN2;
    int   mk = mask[lbase + t];
    float pj[13];
#pragma unroll
    for (int j = 0; j < 13; ++j) pj[j] = __shfl(P, j, 16);
    float s0 = pj[0] * U[0];  s0 = fmaf(pj[4],  U[4],  s0);
    s0 = fmaf(pj[8],  U[8],  s0);  s0 = fmaf(pj[12], U[12], s0);
    float s1 = pj[1] * U[1];  s1 = fmaf(pj[5],  U[5],  s1);  s1 = fmaf(pj[9],  U[9],  s1);
    float s2 = pj[2] * U[2];  s2 = fmaf(pj[6],  U[6],  s2);  s2 = fmaf(pj[10], U[10], s2);
    float s3 = pj[3] * U[3];  s3 = fmaf(pj[7],  U[7],  s3);  s3 = fmaf(pj[11], U[11], s3);
    float s = (s0 + s1) + (s2 + s3);
    float Pn = EXP2F(e2) * s;
    P = mk ? Pn : P;
    if (((t - t0) & 7) == 0) {   // renorm: keep row max in [1,2)
      float mx = P;
#pragma unroll
      for (int o = 1; o < 16; o <<= 1) mx = fmaxf(mx, __shfl_xor(mx, o, 16));
      unsigned eb = (__float_as_uint(mx) >> 23) & 255u;
      float scale = __uint_as_float((254u - eb) << 23);   // 2^(127-eb)
      P *= scale;
      off += (float)((int)eb - 127);
    }
  }
  if (active) Mout[(size_t)bp * 169 + g * 13 + k] = (P > 0.f) ? (LOG2F(P) + off) : -1e30f;

  // ---- numerator partial for this chunk's tokens [t0, t1) ----
  if (tid < 64) {
    float np = 0.f; int cnt = 0;
    for (int t = t0 + tid; t < t1; t += 64) {
      int mk = mask[lbase + t];
      if (mk) {
        int tg = labels[lbase + t];
        int pg = labels[lbase + t - 1];
        np += T[pg * 13 + tg] + logits[(lbase + t) * Lc + tg];
        cnt += 1;
      }
    }
#pragma unroll
    for (int o = 1; o < 64; o <<= 1) {
      np  += __shfl_xor(np, o, 64);
      cnt += __shfl_xor(cnt, o, 64);
    }
    if (tid == 0) { numpart[bp] = np; cntpart[bp] = (float)cnt; }
  }
}

// ---------------------------------------------------------------------------
// Kernel C: per batch: combine 16 chunk matrices (log2 domain) -> denominator;
// assemble numerator from partials; atomicAdd loss.
// ---------------------------------------------------------------------------
__global__ void k_final(const float* __restrict__ logits, const int* __restrict__ mask,
                        const int* __restrict__ labels, const float* __restrict__ startT,
                        const float* __restrict__ endT, const float* __restrict__ Mws,
                        const float* __restrict__ numpart, const float* __restrict__ cntpart,
                        float* __restrict__ out0) {
  const int b = blockIdx.x;
  const int lane = threadIdx.x;
  const int kk = (lane < 13) ? lane : 0;
  const size_t lbase = (size_t)b * Sc;

  // ---- denominator (log2 domain) ----
  float v = (startT[kk] + logits[lbase * Lc + kk]) * INV_LN2;
  for (int p = 0; p < NCHUNK; ++p) {
    const float* Mp = Mws + (size_t)(b * NCHUNK + p) * 169;
    float a[13];
#pragma unroll
    for (int j = 0; j < 13; ++j) a[j] = __shfl(v, j, 64) + Mp[j * 13 + kk];
    float mx = a[0];
#pragma unroll
    for (int j = 1; j < 13; ++j) mx = fmaxf(mx, a[j]);
    float s = 0.f;
#pragma unroll
    for (int j = 0; j < 13; ++j) s += EXP2F(a[j] - mx);
    v = mx + LOG2F(s);
  }
  float x = (lane < 13) ? (v + endT[kk] * INV_LN2) : -1e30f;
  float mx = x;
#pragma unroll
  for (int off = 1; off < 16; off <<= 1) mx = fmaxf(mx, __shfl_xor(mx, off, 16));
  float sx = EXP2F(x - mx);
#pragma unroll
  for (int off = 1; off < 16; off <<= 1) sx += __shfl_xor(sx, off, 16);
  float den = (mx + LOG2F(sx)) * LN2f;   // valid on lanes 0..15

  // ---- numerator from chunk partials (lanes 0..15) ----
  float np = 0.f, cs = 0.f;
  if (lane < NCHUNK) { np = numpart[b * NCHUNK + lane]; cs = cntpart[b * NCHUNK + lane]; }
#pragma unroll
  for (int o = 1; o < 16; o <<= 1) {
    np += __shfl_xor(np, o, 16);
    cs += __shfl_xor(cs, o, 16);
  }
  if (lane == 0) {
    int lab0 = labels[lbase];
    int seqlen = mask[lbase] + (int)(cs + 0.5f);
    int lastTag = labels[lbase + seqlen - 1];
    float num = startT[lab0] + logits[lbase * Lc + lab0] + np + endT[lastTag];
    float llh = num - den;
    atomicAdd(out0, -llh * (1.0f / Bc));
  }
}

extern "C" void kernel_launch(void* const* d_in, const int* in_sizes, int n_in,
                              void* d_out, int out_size, void* d_ws, size_t ws_size,
                              hipStream_t stream) {
  const float* hs     = (const float*)d_in[0];
  const int*   amask  = (const int*)d_in[1];
  const int*   labels = (const int*)d_in[2];
  const float* W      = (const float*)d_in[3];
  const float* bias   = (const float*)d_in[4];
  const float* startT = (const float*)d_in[5];
  const float* endT   = (const float*)d_in[6];
  const float* T      = (const float*)d_in[7];

  float* out    = (float*)d_out;
  float* logits = out + 1;            // output 1 follows the scalar loss
  float* Mws    = (float*)d_ws;       // 512*169 floats = 346 KB
  float* numpart = Mws + (size_t)NBLK * 169;
  float* cntpart = numpart + NBLK;    // total ~350 KB of ws

  k_logits<<<BSc / 128, 512, 0, stream>>>(hs, W, bias, logits);
  k_chunks<<<NBLK, 256, 0, stream>>>(logits, amask, labels, T, Mws, numpart, cntpart, out);
  k_final <<<Bc, 64, 0, stream>>>(logits, amask, labels, startT, endT, Mws, numpart, cntpart, out);
}

// Round 14
// 108.065 us; speedup vs baseline: 8.2292x; 1.2988x over previous
//
#include <hip/hip_runtime.h>
#include <math.h>

#define Lc 13
#define Hc 1024
#define Bc 32
#define Sc 2048
#define BSc (Bc*Sc)
#define CHUNK 128
#define NCHUNK 16
#define NBLK (Bc*NCHUNK)   // 512 chunk blocks

#define NSTRIPE 1024       // 64-row stripes
#define GRID_A  768        // exactly 3 blocks/CU at 53KB LDS -- no packing tail

#define INV_LN2 1.44269504088896340736f
#define LN2f    0.69314718055994530942f

#if __has_builtin(__builtin_amdgcn_exp2f)
#define EXP2F(x) __builtin_amdgcn_exp2f(x)
#else
#define EXP2F(x) exp2f(x)
#endif
#if __has_builtin(__builtin_amdgcn_logf)
#define LOG2F(x) __builtin_amdgcn_logf(x)
#else
#define LOG2F(x) log2f(x)
#endif

// DPP-based partial butterfly: v += lane-permuted v (VALU only, no LDS).
template <int CTRL>
__device__ __forceinline__ float dpp_add(float v) {
  int p = __builtin_amdgcn_update_dpp(0, __float_as_int(v), CTRL, 0xF, 0xF, true);
  return v + __int_as_float(p);
}

// ---------------------------------------------------------------------------
// Kernel A: logits = hs @ W^T + b.  EXACT R10 inner structure (measured best:
// 104us total; 6 waves/SIMD beats every 4-wave variant) + packing fix:
// R10's 1024-block grid at 3 blocks/CU capacity left a 256-block tail
// running 1 block/CU (~+30% wall). Now grid=768 (exactly 3/CU), grid-stride
// over 1024 stripes: blocks 0..255 take stripes {b, b+768} and REUSE their
// staged W (no 2nd prologue); round-robin dispatch spreads the double-work
// blocks one-per-CU -> balanced 4 stripes/CU, no idle phase.
// Lane = rin*16+ch; 16 slices of 64 h; depth-2 prefetch, 3 static slots;
// pure-DPP 16-lane reduction. (512,6): ~85 VGPR tier, 3 blocks/CU.
// ---------------------------------------------------------------------------
__global__ __launch_bounds__(512, 6)
void k_logits(const float* __restrict__ A, const float* __restrict__ W,
              const float* __restrict__ bias, float* __restrict__ out) {
  __shared__ float Wl[Lc * Hc];   // 53.2 KB
  const int tid = threadIdx.x;
  const int ln  = tid & 63;
  const int wv  = tid >> 6;            // 0..7
  const int rin = ln >> 4;             // row within 4-row group
  const int ch  = ln & 15;             // 16B chunk within 64-float slice

  for (int stripe = blockIdx.x; stripe < NSTRIPE; stripe += GRID_A) {
    const size_t rowBase = (size_t)stripe * 64 + (size_t)wv * 8;
    const float* A0 = A + (rowBase + rin) * (size_t)Hc + ch * 4;  // g=0 row
    const float* A1 = A0 + 4 * (size_t)Hc;                        // g=1 row

    // depth-2 prefetch: slices 0,1 issued before W-stage / compute
    float4 buf00 = *(const float4*)(A0);
    float4 buf10 = *(const float4*)(A1);
    float4 buf01 = *(const float4*)(A0 + 64);
    float4 buf11 = *(const float4*)(A1 + 64);
    __builtin_amdgcn_sched_barrier(0);   // pin A prefetch first

    if (stripe == (int)blockIdx.x) {     // stage W once per block (uniform)
      const float4* Wg4 = (const float4*)W;
      float4* Wl4 = (float4*)Wl;
#pragma unroll
      for (int i = 0; i < 7; ++i) {
        int idx = tid + i * 512;
        if (idx < Lc * (Hc / 4)) Wl4[idx] = Wg4[idx];
      }
      __syncthreads();
    }

    float acc0[Lc], acc1[Lc];
#pragma unroll
    for (int l = 0; l < Lc; ++l) { acc0[l] = 0.f; acc1[l] = 0.f; }

    float4 buf02, buf12;   // slot 2 of the 3-slot rotation
#pragma unroll
    for (int kk = 0; kk < 16; ++kk) {
      // consume slot kk%3 (static under full unroll)
      float4 a0 = (kk % 3 == 0) ? buf00 : (kk % 3 == 1) ? buf01 : buf02;
      float4 a1 = (kk % 3 == 0) ? buf10 : (kk % 3 == 1) ? buf11 : buf12;
      // issue slice kk+2 into slot (kk+2)%3
      if (kk + 2 < 16) {
        float4 n0 = *(const float4*)(A0 + (kk + 2) * 64);
        float4 n1 = *(const float4*)(A1 + (kk + 2) * 64);
        if ((kk + 2) % 3 == 0)      { buf00 = n0; buf10 = n1; }
        else if ((kk + 2) % 3 == 1) { buf01 = n0; buf11 = n1; }
        else                        { buf02 = n0; buf12 = n1; }
      }
      const float* wb = &Wl[kk * 64 + ch * 4];
#pragma unroll
      for (int l = 0; l < Lc; ++l) {
        float4 w = *(const float4*)(wb + l * Hc);   // shared g=0/1, bcast x4
        acc0[l] = fmaf(a0.x, w.x, acc0[l]); acc0[l] = fmaf(a0.y, w.y, acc0[l]);
        acc0[l] = fmaf(a0.z, w.z, acc0[l]); acc0[l] = fmaf(a0.w, w.w, acc0[l]);
        acc1[l] = fmaf(a1.x, w.x, acc1[l]); acc1[l] = fmaf(a1.y, w.y, acc1[l]);
        acc1[l] = fmaf(a1.z, w.z, acc1[l]); acc1[l] = fmaf(a1.w, w.w, acc1[l]);
      }
    }

    // reduce within 16-lane group: xor1,xor2 (quad_perm), ^7, ^15 (mirrors)
#pragma unroll
    for (int l = 0; l < Lc; ++l) {
      float s0 = acc0[l], s1 = acc1[l];
      s0 = dpp_add<0xB1>(s0);   s1 = dpp_add<0xB1>(s1);
      s0 = dpp_add<0x4E>(s0);   s1 = dpp_add<0x4E>(s1);
      s0 = dpp_add<0x141>(s0);  s1 = dpp_add<0x141>(s1);
      s0 = dpp_add<0x140>(s0);  s1 = dpp_add<0x140>(s1);
      acc0[l] = s0; acc1[l] = s1;
    }
    float ov0 = 0.f, ov1 = 0.f;
#pragma unroll
    for (int l = 0; l < Lc; ++l) {
      float bl = bias[l];
      ov0 = (ch == l) ? acc0[l] + bl : ov0;
      ov1 = (ch == l) ? acc1[l] + bl : ov1;
    }
    if (ch < Lc) {
      out[(rowBase + rin) * Lc + ch]     = ov0;
      out[(rowBase + 4 + rin) * Lc + ch] = ov1;
    }
  }
}

// ---------------------------------------------------------------------------
// Kernel B: per (batch, chunk) 13x13 transfer matrix, LINEAR domain
// (13 shfl + 13 fma + 1 exp2 per step; exponent-extract renorm every 8).
// Wave 0 also computes the chunk's numerator partial. Block 0 zeroes out0.
// ---------------------------------------------------------------------------
__global__ void k_chunks(const float* __restrict__ logits, const int* __restrict__ mask,
                         const int* __restrict__ labels, const float* __restrict__ T,
                         float* __restrict__ Mout, float* __restrict__ numpart,
                         float* __restrict__ cntpart, float* __restrict__ out0) {
  const int bp = blockIdx.x;
  const int b  = bp >> 4;       // NCHUNK == 16
  const int p  = bp & 15;
  const int tid = threadIdx.x;
  if (bp == 0 && tid == 0) out0[0] = 0.f;   // zero loss accumulator for k_final
  const int g = tid >> 4;
  const int k = tid & 15;
  const int kk = (k < 13) ? k : 0;
  const int gg = (g < 13) ? g : 0;
  const bool active = (g < 13) && (k < 13);
  const size_t lbase = (size_t)b * Sc;
  const int t0 = 1 + p * CHUNK;
  const int t1 = min(t0 + CHUNK, Sc);

  float U[13];   // column kk of exp(T)
#pragma unroll
  for (int j = 0; j < 13; ++j) U[j] = EXP2F(T[j * 13 + kk] * INV_LN2);

  float e0 = logits[(lbase + t0) * Lc + kk] * INV_LN2;
  int   m0 = mask[lbase + t0];
  float P = m0 ? EXP2F(T[gg * 13 + kk] * INV_LN2 + e0) : ((g == k) ? 1.f : 0.f);
  float off = 0.f;

  for (int t = t0 + 1; t < t1; ++t) {
    float e2 = logits[(lbase + t) * Lc + kk] * INV_LN2;
    int   mk = mask[lbase + t];
    float pj[13];
#pragma unroll
    for (int j = 0; j < 13; ++j) pj[j] = __shfl(P, j, 16);
    float s0 = pj[0] * U[0];  s0 = fmaf(pj[4],  U[4],  s0);
    s0 = fmaf(pj[8],  U[8],  s0);  s0 = fmaf(pj[12], U[12], s0);
    float s1 = pj[1] * U[1];  s1 = fmaf(pj[5],  U[5],  s1);  s1 = fmaf(pj[9],  U[9],  s1);
    float s2 = pj[2] * U[2];  s2 = fmaf(pj[6],  U[6],  s2);  s2 = fmaf(pj[10], U[10], s2);
    float s3 = pj[3] * U[3];  s3 = fmaf(pj[7],  U[7],  s3);  s3 = fmaf(pj[11], U[11], s3);
    float s = (s0 + s1) + (s2 + s3);
    float Pn = EXP2F(e2) * s;
    P = mk ? Pn : P;
    if (((t - t0) & 7) == 0) {   // renorm: keep row max in [1,2)
      float mx = P;
#pragma unroll
      for (int o = 1; o < 16; o <<= 1) mx = fmaxf(mx, __shfl_xor(mx, o, 16));
      unsigned eb = (__float_as_uint(mx) >> 23) & 255u;
      float scale = __uint_as_float((254u - eb) << 23);   // 2^(127-eb)
      P *= scale;
      off += (float)((int)eb - 127);
    }
  }
  if (active) Mout[(size_t)bp * 169 + g * 13 + k] = (P > 0.f) ? (LOG2F(P) + off) : -1e30f;

  // ---- numerator partial for this chunk's tokens [t0, t1) ----
  if (tid < 64) {
    float np = 0.f; int cnt = 0;
    for (int t = t0 + tid; t < t1; t += 64) {
      int mk = mask[lbase + t];
      if (mk) {
        int tg = labels[lbase + t];
        int pg = labels[lbase + t - 1];
        np += T[pg * 13 + tg] + logits[(lbase + t) * Lc + tg];
        cnt += 1;
      }
    }
#pragma unroll
    for (int o = 1; o < 64; o <<= 1) {
      np  += __shfl_xor(np, o, 64);
      cnt += __shfl_xor(cnt, o, 64);
    }
    if (tid == 0) { numpart[bp] = np; cntpart[bp] = (float)cnt; }
  }
}

// ---------------------------------------------------------------------------
// Kernel C: per batch: combine 16 chunk matrices (log2 domain) -> denominator;
// assemble numerator from partials; atomicAdd loss.
// ---------------------------------------------------------------------------
__global__ void k_final(const float* __restrict__ logits, const int* __restrict__ mask,
                        const int* __restrict__ labels, const float* __restrict__ startT,
                        const float* __restrict__ endT, const float* __restrict__ Mws,
                        const float* __restrict__ numpart, const float* __restrict__ cntpart,
                        float* __restrict__ out0) {
  const int b = blockIdx.x;
  const int lane = threadIdx.x;
  const int kk = (lane < 13) ? lane : 0;
  const size_t lbase = (size_t)b * Sc;

  // ---- denominator (log2 domain) ----
  float v = (startT[kk] + logits[lbase * Lc + kk]) * INV_LN2;
  for (int p = 0; p < NCHUNK; ++p) {
    const float* Mp = Mws + (size_t)(b * NCHUNK + p) * 169;
    float a[13];
#pragma unroll
    for (int j = 0; j < 13; ++j) a[j] = __shfl(v, j, 64) + Mp[j * 13 + kk];
    float mx = a[0];
#pragma unroll
    for (int j = 1; j < 13; ++j) mx = fmaxf(mx, a[j]);
    float s = 0.f;
#pragma unroll
    for (int j = 0; j < 13; ++j) s += EXP2F(a[j] - mx);
    v = mx + LOG2F(s);
  }
  float x = (lane < 13) ? (v + endT[kk] * INV_LN2) : -1e30f;
  float mx = x;
#pragma unroll
  for (int off = 1; off < 16; off <<= 1) mx = fmaxf(mx, __shfl_xor(mx, off, 16));
  float sx = EXP2F(x - mx);
#pragma unroll
  for (int off = 1; off < 16; off <<= 1) sx += __shfl_xor(sx, off, 16);
  float den = (mx + LOG2F(sx)) * LN2f;   // valid on lanes 0..15

  // ---- numerator from chunk partials (lanes 0..15) ----
  float np = 0.f, cs = 0.f;
  if (lane < NCHUNK) { np = numpart[b * NCHUNK + lane]; cs = cntpart[b * NCHUNK + lane]; }
#pragma unroll
  for (int o = 1; o < 16; o <<= 1) {
    np += __shfl_xor(np, o, 16);
    cs += __shfl_xor(cs, o, 16);
  }
  if (lane == 0) {
    int lab0 = labels[lbase];
    int seqlen = mask[lbase] + (int)(cs + 0.5f);
    int lastTag = labels[lbase + seqlen - 1];
    float num = startT[lab0] + logits[lbase * Lc + lab0] + np + endT[lastTag];
    float llh = num - den;
    atomicAdd(out0, -llh * (1.0f / Bc));
  }
}

extern "C" void kernel_launch(void* const* d_in, const int* in_sizes, int n_in,
                              void* d_out, int out_size, void* d_ws, size_t ws_size,
                              hipStream_t stream) {
  const float* hs     = (const float*)d_in[0];
  const int*   amask  = (const int*)d_in[1];
  const int*   labels = (const int*)d_in[2];
  const float* W      = (const float*)d_in[3];
  const float* bias   = (const float*)d_in[4];
  const float* startT = (const float*)d_in[5];
  const float* endT   = (const float*)d_in[6];
  const float* T      = (const float*)d_in[7];

  float* out    = (float*)d_out;
  float* logits = out + 1;            // output 1 follows the scalar loss
  float* Mws    = (float*)d_ws;       // 512*169 floats = 346 KB
  float* numpart = Mws + (size_t)NBLK * 169;
  float* cntpart = numpart + NBLK;    // total ~350 KB of ws

  k_logits<<<GRID_A, 512, 0, stream>>>(hs, W, bias, logits);
  k_chunks<<<NBLK, 256, 0, stream>>>(logits, amask, labels, T, Mws, numpart, cntpart, out);
  k_final <<<Bc, 64, 0, stream>>>(logits, amask, labels, startT, endT, Mws, numpart, cntpart, out);
}